// Round 2
// baseline (1668.249 us; speedup 1.0000x reference)
//
#include <hip/hip_runtime.h>
#include <hip/hip_bf16.h>

// Problem constants
#define BB 16
#define NN 4096
#define CC 768
#define HH 12
#define HD 64
#define SCALE_F 0.125f

typedef unsigned short u16;
typedef __bf16 bf16x8 __attribute__((ext_vector_type(8)));
typedef float f32x4 __attribute__((ext_vector_type(4)));
typedef u16 u16x4 __attribute__((ext_vector_type(4)));

__device__ __forceinline__ u16 f2bf(float f) {
  union { __hip_bfloat16 h; u16 u; } v;
  v.h = __float2bfloat16(f);
  return v.u;
}

__device__ __forceinline__ float bf2f(u16 u) {
  union { unsigned int i; float f; } v;
  v.i = ((unsigned int)u) << 16;
  return v.f;
}

// split f into bf16 hi + bf16 lo (hi+lo captures ~16-17 mantissa bits)
__device__ __forceinline__ void split2(float f, u16& hi, u16& lo) {
  hi = f2bf(f);
  lo = f2bf(f - bf2f(hi));
}

__device__ __forceinline__ f32x4 mfma16(bf16x8 a, bf16x8 b, f32x4 c) {
  return __builtin_amdgcn_mfma_f32_16x16x32_bf16(a, b, c, 0, 0, 0);
}

union bfr_u { bf16x8 v; u16 u[8]; };

// load 8 contiguous fp32 and split into hi/lo bf16x8 fragments
__device__ __forceinline__ void load_split8(const float* p, bf16x8& hi, bf16x8& lo) {
  f32x4 v0 = *(const f32x4*)p;
  f32x4 v1 = *(const f32x4*)(p + 4);
  bfr_u h, l;
  for (int i = 0; i < 4; i++) split2(v0[i], h.u[i], l.u[i]);
  for (int i = 0; i < 4; i++) split2(v1[i], h.u[4 + i], l.u[4 + i]);
  hi = h.v; lo = l.v;
}

// ---------------------------------------------------------------------------
// Kernel 0: transpose + cast W [768][1536] fp32 -> WT_hi/WT_lo [1536][768] bf16
// ---------------------------------------------------------------------------
__global__ __launch_bounds__(256) void wtrans_kernel(const float* __restrict__ w0,
                                                     const float* __restrict__ w1,
                                                     u16* __restrict__ WTh,
                                                     u16* __restrict__ WTl) {
  __shared__ float tile[64][65];
  const float* W = blockIdx.z ? w1 : w0;
  const size_t obase = (size_t)blockIdx.z * (1536 * 768);
  const int col0 = blockIdx.x * 64;  // 24 tiles
  const int c0   = blockIdx.y * 64;  // 12 tiles
  const int t = threadIdx.x;
  const int lc = t & 63;
  const int lr = t >> 6;
  for (int r = lr; r < 64; r += 4)
    tile[r][lc] = W[(size_t)(c0 + r) * 1536 + col0 + lc];  // tile[c_off][col_off]
  __syncthreads();
  for (int r = lr; r < 64; r += 4) {
    u16 hi, lo;
    split2(tile[lc][r], hi, lo);
    WTh[obase + (size_t)(col0 + r) * CC + c0 + lc] = hi;
    WTl[obase + (size_t)(col0 + r) * CC + c0 + lc] = lo;
  }
}

// ---------------------------------------------------------------------------
// Kernel 1: per-batch Gram G_b = X_b^T X_b  (bf16 MFMA, symmetric: 21 tile-pairs)
// G stored as split bf16 pair (G_hi + G_lo ~= fp32-accurate).
// LDS tile layout (transposed, swizzled):
//   addr_u16(c,k) = (c>>2)*168 + (c&3)*8 + (k>>3)*32 + (k&7),  c in [0,128), k in [0,32)
// ---------------------------------------------------------------------------
__device__ __forceinline__ int gtile_addr(int c, int k) {
  return (c >> 2) * 168 + (c & 3) * 8 + (k >> 3) * 32 + (k & 7);
}

__global__ __launch_bounds__(256) void gram_kernel(const float* __restrict__ x0,
                                                   const float* __restrict__ x1,
                                                   u16* __restrict__ Gh,
                                                   u16* __restrict__ Gl) {
  __shared__ u16 As[32 * 168];
  __shared__ u16 Bs[32 * 168];

  int idx = blockIdx.x;  // 0..20 -> (ti,tj) with ti<=tj, 6x6 tiles
  int ti = 0;
  while (idx >= 6 - ti) { idx -= 6 - ti; ti++; }
  const int tj = ti + idx;
  const int b = blockIdx.y, modal = blockIdx.z;
  const float* X = (modal ? x1 : x0) + (size_t)b * NN * CC;
  const size_t goff = (size_t)(modal * BB + b) * CC * CC;
  u16* Ghb = Gh + goff;
  u16* Glb = Gl + goff;

  const int t = threadIdx.x;
  const int lane = t & 63;
  const int w = t >> 6;
  const int lm = lane & 15;
  const int q = lane >> 4;
  const int wm = (w & 1) * 64;
  const int wn = (w >> 1) * 64;

  const int cq = t & 31;        // c-quad: c = 4*cq + ci
  const int nb = (t >> 5) * 4;  // k (row) base: 0,4,...,28

  f32x4 acc[4][4];
  for (int i = 0; i < 4; i++)
    for (int j = 0; j < 4; j++) { f32x4 z = {0.f, 0.f, 0.f, 0.f}; acc[i][j] = z; }

  const bool diag = (ti == tj);

  for (int kc = 0; kc < NN / 32; kc++) {
    const int n0 = kc * 32;
    __syncthreads();
    {
      const float* src = X + (size_t)(n0 + nb) * CC + ti * 128 + cq * 4;
      float4 r0 = *(const float4*)(src);
      float4 r1 = *(const float4*)(src + CC);
      float4 r2 = *(const float4*)(src + 2 * CC);
      float4 r3 = *(const float4*)(src + 3 * CC);
      u16x4 p0 = {f2bf(r0.x), f2bf(r1.x), f2bf(r2.x), f2bf(r3.x)};
      u16x4 p1 = {f2bf(r0.y), f2bf(r1.y), f2bf(r2.y), f2bf(r3.y)};
      u16x4 p2 = {f2bf(r0.z), f2bf(r1.z), f2bf(r2.z), f2bf(r3.z)};
      u16x4 p3 = {f2bf(r0.w), f2bf(r1.w), f2bf(r2.w), f2bf(r3.w)};
      *(u16x4*)&As[gtile_addr(4 * cq + 0, nb)] = p0;
      *(u16x4*)&As[gtile_addr(4 * cq + 1, nb)] = p1;
      *(u16x4*)&As[gtile_addr(4 * cq + 2, nb)] = p2;
      *(u16x4*)&As[gtile_addr(4 * cq + 3, nb)] = p3;
    }
    if (!diag) {
      const float* src = X + (size_t)(n0 + nb) * CC + tj * 128 + cq * 4;
      float4 r0 = *(const float4*)(src);
      float4 r1 = *(const float4*)(src + CC);
      float4 r2 = *(const float4*)(src + 2 * CC);
      float4 r3 = *(const float4*)(src + 3 * CC);
      u16x4 p0 = {f2bf(r0.x), f2bf(r1.x), f2bf(r2.x), f2bf(r3.x)};
      u16x4 p1 = {f2bf(r0.y), f2bf(r1.y), f2bf(r2.y), f2bf(r3.y)};
      u16x4 p2 = {f2bf(r0.z), f2bf(r1.z), f2bf(r2.z), f2bf(r3.z)};
      u16x4 p3 = {f2bf(r0.w), f2bf(r1.w), f2bf(r2.w), f2bf(r3.w)};
      *(u16x4*)&Bs[gtile_addr(4 * cq + 0, nb)] = p0;
      *(u16x4*)&Bs[gtile_addr(4 * cq + 1, nb)] = p1;
      *(u16x4*)&Bs[gtile_addr(4 * cq + 2, nb)] = p2;
      *(u16x4*)&Bs[gtile_addr(4 * cq + 3, nb)] = p3;
    }
    __syncthreads();
    const u16* Bp = diag ? As : Bs;
    bf16x8 af[4], bfr[4];
    for (int mt = 0; mt < 4; mt++)
      af[mt] = *(const bf16x8*)&As[gtile_addr(wm + mt * 16 + lm, q * 8)];
    for (int nt = 0; nt < 4; nt++)
      bfr[nt] = *(const bf16x8*)&Bp[gtile_addr(wn + nt * 16 + lm, q * 8)];
    for (int mt = 0; mt < 4; mt++)
      for (int nt = 0; nt < 4; nt++)
        acc[mt][nt] = mfma16(af[mt], bfr[nt], acc[mt][nt]);
  }

  // Epilogue: C/D layout col=lane&15, row=4*q+reg; store split hi/lo
  for (int mt = 0; mt < 4; mt++)
    for (int nt = 0; nt < 4; nt++) {
      const int row0 = ti * 128 + wm + mt * 16 + q * 4;
      const int col  = tj * 128 + wn + nt * 16 + lm;
      f32x4 v = acc[mt][nt];
      u16 hi[4], lo[4];
      for (int i = 0; i < 4; i++) split2(v[i], hi[i], lo[i]);
      for (int i = 0; i < 4; i++) {
        Ghb[(size_t)(row0 + i) * CC + col] = hi[i];
        Glb[(size_t)(row0 + i) * CC + col] = lo[i];
      }
      if (!diag) {  // mirror block (G symmetric)
        u16x4 ph = {hi[0], hi[1], hi[2], hi[3]};
        u16x4 pl = {lo[0], lo[1], lo[2], lo[3]};
        *(u16x4*)&Ghb[(size_t)col * CC + row0] = ph;
        *(u16x4*)&Glb[(size_t)col * CC + row0] = pl;
      }
    }
}

// ---------------------------------------------------------------------------
// Kernel 2: per (b,h,modal): ctx = softmax_d( SCALE * Wk_h^T G_b Wv_h )
// Split-bf16 (3-chain) MFMA throughout; U kept fp32 in LDS; 4 r-passes of 192.
// ctx stored TRANSPOSED [e][d] bf16.
// ---------------------------------------------------------------------------
__global__ __launch_bounds__(256) void ctx_kernel(const u16* __restrict__ WTh,
                                                  const u16* __restrict__ WTl,
                                                  const u16* __restrict__ Gh,
                                                  const u16* __restrict__ Gl,
                                                  u16* __restrict__ ctxT) {
  __shared__ __align__(16) float Us[64 * 196];  // 50176 B; [e][r_local], stride 196
  float* cs = Us;                               // later aliased: logits [d][e], stride 68

  const int h = blockIdx.x, b = blockIdx.y, modal = blockIdx.z;
  const size_t goff = (size_t)(modal * BB + b) * CC * CC;
  const u16* Ghb = Gh + goff;
  const u16* Glb = Gl + goff;
  const size_t vrow = (size_t)modal * 1536 + 768 + h * HD;  // Wv^T rows [e][c]
  const size_t krow = (size_t)modal * 1536 + h * HD;        // Wk^T rows [d][c]
  u16* cout = ctxT + ((size_t)((modal * BB + b) * HH + h)) * (HD * HD);

  const int t = threadIdx.x;
  const int lane = t & 63, w = t >> 6;
  const int lm = lane & 15, q = lane >> 4;
  const int d0 = w * 16;  // stage-2 m-tile per wave

  f32x4 acc2[4];
  for (int i = 0; i < 4; i++) { f32x4 z = {0.f, 0.f, 0.f, 0.f}; acc2[i] = z; }

  for (int p = 0; p < 4; p++) {
    const int rbase = p * 192;
    __syncthreads();  // protect Us from previous pass stage-2 readers
    // Stage 1: U[r][e] = sum_c G[r][c] * Wv[c][e], r-local in [0,192)
    for (int mi = 0; mi < 3; mi++) {
      const int row0 = w * 48 + mi * 16;
      const size_t r = (size_t)(rbase + row0 + lm) * CC;
      f32x4 acc[4];
      for (int i = 0; i < 4; i++) { f32x4 z = {0.f, 0.f, 0.f, 0.f}; acc[i] = z; }
      for (int kc = 0; kc < 24; kc++) {
        const int co = kc * 32 + q * 8;
        bf16x8 ah = *(const bf16x8*)&Ghb[r + co];
        bf16x8 al = *(const bf16x8*)&Glb[r + co];
        for (int nt = 0; nt < 4; nt++) {
          bf16x8 bh = *(const bf16x8*)&WTh[(vrow + nt * 16 + lm) * CC + co];
          bf16x8 bl = *(const bf16x8*)&WTl[(vrow + nt * 16 + lm) * CC + co];
          acc[nt] = mfma16(ah, bh, acc[nt]);
          acc[nt] = mfma16(al, bh, acc[nt]);
          acc[nt] = mfma16(ah, bl, acc[nt]);
        }
      }
      for (int nt = 0; nt < 4; nt++)  // D: row=q*4+i -> r_local, col=lm -> e
        *(f32x4*)&Us[(nt * 16 + lm) * 196 + row0 + q * 4] = acc[nt];
    }
    __syncthreads();
    // Stage 2 partial accumulate: ctx[d][e] += sum_{r in pass} Wk[r][d] * U[r][e]
    for (int rc = 0; rc < 6; rc++) {
      bf16x8 ah = *(const bf16x8*)&WTh[(krow + d0 + lm) * CC + rbase + rc * 32 + q * 8];
      bf16x8 al = *(const bf16x8*)&WTl[(krow + d0 + lm) * CC + rbase + rc * 32 + q * 8];
      for (int nt = 0; nt < 4; nt++) {
        bf16x8 bh, bl;
        load_split8(&Us[(nt * 16 + lm) * 196 + rc * 32 + q * 8], bh, bl);
        acc2[nt] = mfma16(ah, bh, acc2[nt]);
        acc2[nt] = mfma16(al, bh, acc2[nt]);
        acc2[nt] = mfma16(ah, bl, acc2[nt]);
      }
    }
  }
  __syncthreads();  // everyone done reading Us before aliasing as cs
  for (int nt = 0; nt < 4; nt++) {
    const int e = nt * 16 + lm;
    for (int i = 0; i < 4; i++)
      cs[(d0 + q * 4 + i) * 68 + e] = acc2[nt][i] * SCALE_F;
  }
  __syncthreads();
  if (t < 64) {
    const int e = t;
    float mx = -1e30f;
    for (int d = 0; d < 64; d++) mx = fmaxf(mx, cs[d * 68 + e]);
    float s = 0.f;
    for (int d = 0; d < 64; d++) s += __expf(cs[d * 68 + e] - mx);
    const float inv = 1.f / s;
    for (int d = 0; d < 64; d++)
      cout[e * 64 + d] = f2bf(__expf(cs[d * 68 + e] - mx) * inv);  // [e][d]
  }
}

// ---------------------------------------------------------------------------
// Kernel 3: out[modal][b, n, h*64+e] = sum_d X_modal[b,n,h*64+d] * ctx[modal^1][b,h,d,e]
// 32 rows per workgroup; X staged in LDS bf16 (natural layout, stride 776).
// ---------------------------------------------------------------------------
__global__ __launch_bounds__(256) void out_kernel(const float* __restrict__ x0,
                                                  const float* __restrict__ x1,
                                                  const u16* __restrict__ ctxT,
                                                  float* __restrict__ out) {
  __shared__ u16 Xs[32 * 776];  // 49664 u16
  const int nt0 = blockIdx.x;   // 128 tiles of 32 rows
  const int b = blockIdx.y, modal = blockIdx.z;
  const float* X = (modal ? x1 : x0) + (size_t)b * NN * CC + (size_t)nt0 * 32 * CC;
  const u16* ctxb = ctxT + (size_t)(((modal ^ 1) * BB + b) * HH) * (HD * HD);
  float* O = out + (size_t)modal * BB * NN * CC + (size_t)b * NN * CC + (size_t)nt0 * 32 * CC;

  const int t = threadIdx.x;
  for (int idx = t; idx < 32 * 192; idx += 256) {
    const int r = idx / 192, cq = idx % 192;
    float4 v = *(const float4*)&X[(size_t)r * CC + cq * 4];
    u16x4 pk = {f2bf(v.x), f2bf(v.y), f2bf(v.z), f2bf(v.w)};
    *(u16x4*)&Xs[r * 776 + cq * 4] = pk;
  }
  __syncthreads();

  const int lane = t & 63, w = t >> 6;
  const int lm = lane & 15, q = lane >> 4;
  const int mt = w & 1;          // row-tile 0/1 (16 rows each)
  const int hh = (w >> 1) * 6;   // head base
  for (int hi = 0; hi < 6; hi++) {
    const int h = hh + hi;
    bf16x8 a0 = *(const bf16x8*)&Xs[(mt * 16 + lm) * 776 + h * 64 + 0 + q * 8];
    bf16x8 a1 = *(const bf16x8*)&Xs[(mt * 16 + lm) * 776 + h * 64 + 32 + q * 8];
    const u16* ch = ctxb + (size_t)h * (HD * HD);  // [e][d]
    for (int et = 0; et < 4; et++) {
      f32x4 acc = {0.f, 0.f, 0.f, 0.f};
      bf16x8 b0 = *(const bf16x8*)&ch[(et * 16 + lm) * 64 + 0 + q * 8];
      bf16x8 b1 = *(const bf16x8*)&ch[(et * 16 + lm) * 64 + 32 + q * 8];
      acc = mfma16(a0, b0, acc);
      acc = mfma16(a1, b1, acc);
      for (int i = 0; i < 4; i++)
        O[(size_t)(mt * 16 + q * 4 + i) * CC + h * 64 + et * 16 + lm] = acc[i];
    }
  }
}

// ---------------------------------------------------------------------------
extern "C" void kernel_launch(void* const* d_in, const int* in_sizes, int n_in,
                              void* d_out, int out_size, void* d_ws, size_t ws_size,
                              hipStream_t stream) {
  (void)in_sizes; (void)n_in; (void)out_size; (void)ws_size;
  const float* rgb   = (const float*)d_in[0];
  const float* dep   = (const float*)d_in[1];
  const float* w_rgb = (const float*)d_in[2];
  const float* w_dep = (const float*)d_in[3];
  float* out = (float*)d_out;

  char* ws = (char*)d_ws;
  u16* WTh = (u16*)ws;                       // 2*1536*768*2  = 4,718,592 B
  u16* WTl = (u16*)(ws + 4718592);           // 4,718,592 B
  u16* Gh  = (u16*)(ws + 9437184);           // 2*16*768*768*2 = 37,748,736 B
  u16* Gl  = (u16*)(ws + 47185920);          // 37,748,736 B
  u16* CT  = (u16*)(ws + 84934656);          // 2*16*12*64*64*2 = 3,145,728 B
                                             // total 88,080,384 B

  wtrans_kernel<<<dim3(24, 12, 2), 256, 0, stream>>>(w_rgb, w_dep, WTh, WTl);
  gram_kernel<<<dim3(21, 16, 2), 256, 0, stream>>>(rgb, dep, Gh, Gl);
  ctx_kernel<<<dim3(HH, BB, 2), 256, 0, stream>>>(WTh, WTl, Gh, Gl, CT);
  out_kernel<<<dim3(128, BB, 2), 256, 0, stream>>>(rgb, dep, CT, out);
}